// Round 2
// baseline (2625.337 us; speedup 1.0000x reference)
//
#include <hip/hip_runtime.h>
#include <hip/hip_bf16.h>
#include <hip/hip_cooperative_groups.h>

namespace cg = cooperative_groups;

// Problem constants (match reference)
#define NN 100000
#define NE 3200000
#define F_IN 512
#define NHID 64
#define NCLS 40

// Radix-partition CSR build params
#define NB2 512   // row buckets
#define RPB2 196  // rows per bucket (512*196 = 100352 >= NN)
#define CHK 4096  // edges per chunk
#define NCH 782   // ceil(NE/CHK)
#define EPT 16    // edges per thread in P3 (CHK/256)
#define ECAP 7168 // emit LDS capacity (mean 6250, sigma 79 -> +11.6 sigma)
#define TOT (NB2 * NCH)  // 400,384 = 391 * 1024 exactly
#define NSB 391   // scan blocks

#define TPN 5     // threads per node in propagation (8 classes each)
#define PGRID 1024  // cooperative grid blocks (4/CU on 256 CUs)

typedef int v4i __attribute__((ext_vector_type(4)));
typedef int v2i __attribute__((ext_vector_type(2)));

// bf16 helpers (exact up-convert; RNE down-convert)
__device__ __forceinline__ float bf2f(unsigned short u) {
  return __uint_as_float((unsigned)u << 16);
}
__device__ __forceinline__ unsigned short f2bf(float f) {
  unsigned u = __float_as_uint(f);
  u += 0x7FFFu + ((u >> 16) & 1u);  // round-to-nearest-even
  return (unsigned short)(u >> 16);
}
// packed-bf16 (uint = 2 classes) helpers
__device__ __forceinline__ float blo(unsigned u) {
  return __uint_as_float(u << 16);
}
__device__ __forceinline__ float bhi(unsigned u) {
  return __uint_as_float(u & 0xffff0000u);
}
__device__ __forceinline__ unsigned pk(float l, float h) {
  return (unsigned)f2bf(l) | ((unsigned)f2bf(h) << 16);
}

// ---------------------------------------------------------------------------
// GEMM1: H[N,64] = relu(F[N,512] @ W1[512,64] + b1)
// ---------------------------------------------------------------------------
__global__ __launch_bounds__(256) void gemm1_kernel(
    const float* __restrict__ F, const float* __restrict__ W1,
    const float* __restrict__ b1, float* __restrict__ H) {
  __shared__ float As[16][68];
  __shared__ float Bs[16][64];
  const int tid = threadIdx.x;
  const int m0 = blockIdx.x * 64;
  const int ty = tid >> 4;
  const int tx = tid & 15;
  const int lrowA = tid >> 2;
  const int lkA = (tid & 3) * 4;
  const int lkB = tid >> 4;
  const int lcolB = (tid & 15) * 4;
  const bool rowok = (m0 + lrowA) < NN;
  const int rclamp = rowok ? (m0 + lrowA) : (NN - 1);
  const float* Fb = F + (long)rclamp * F_IN + lkA;

  float acc[4][4] = {};
  for (int k0 = 0; k0 < F_IN; k0 += 16) {
    float4 fa = *(const float4*)(Fb + k0);
    if (!rowok) fa = make_float4(0.f, 0.f, 0.f, 0.f);
    float4 wb = *(const float4*)(W1 + (long)(k0 + lkB) * NHID + lcolB);
    __syncthreads();
    As[lkA + 0][lrowA] = fa.x;
    As[lkA + 1][lrowA] = fa.y;
    As[lkA + 2][lrowA] = fa.z;
    As[lkA + 3][lrowA] = fa.w;
    *(float4*)&Bs[lkB][lcolB] = wb;
    __syncthreads();
#pragma unroll
    for (int kk = 0; kk < 16; ++kk) {
      float4 a = *(const float4*)&As[kk][ty * 4];
      float4 b = *(const float4*)&Bs[kk][tx * 4];
      float av[4] = {a.x, a.y, a.z, a.w};
      float bv[4] = {b.x, b.y, b.z, b.w};
#pragma unroll
      for (int i = 0; i < 4; ++i)
#pragma unroll
        for (int j = 0; j < 4; ++j) acc[i][j] = fmaf(av[i], bv[j], acc[i][j]);
    }
  }
  float4 bb = *(const float4*)(b1 + tx * 4);
  float bv[4] = {bb.x, bb.y, bb.z, bb.w};
#pragma unroll
  for (int i = 0; i < 4; ++i) {
    int r = m0 + ty * 4 + i;
    if (r < NN) {
      float4 o;
      o.x = fmaxf(acc[i][0] + bv[0], 0.f);
      o.y = fmaxf(acc[i][1] + bv[1], 0.f);
      o.z = fmaxf(acc[i][2] + bv[2], 0.f);
      o.w = fmaxf(acc[i][3] + bv[3], 0.f);
      *(float4*)(H + (long)r * NHID + tx * 4) = o;
    }
  }
}

// ---------------------------------------------------------------------------
// GEMM2: X0b (bf16) = H @ W2 + b2.  (teleport term h consumed in bf16)
// ---------------------------------------------------------------------------
__global__ __launch_bounds__(256) void gemm2_kernel(
    const float* __restrict__ H, const float* __restrict__ W2,
    const float* __restrict__ b2, ushort4* __restrict__ X0b) {
  __shared__ float Ws[NHID * NCLS];
  __shared__ float bs[NCLS];
  const int tid = threadIdx.x;
  for (int i = tid; i < NHID * NCLS; i += 256) Ws[i] = W2[i];
  if (tid < NCLS) bs[tid] = b2[tid];
  __syncthreads();
  const int node = blockIdx.x * 256 + tid;
  if (node >= NN) return;
  float acc[NCLS];
#pragma unroll
  for (int j = 0; j < NCLS; ++j) acc[j] = bs[j];
  const float4* h4 = (const float4*)(H + (long)node * NHID);
#pragma unroll
  for (int kq = 0; kq < 16; ++kq) {
    float4 h = h4[kq];
    float hv[4] = {h.x, h.y, h.z, h.w};
#pragma unroll
    for (int u = 0; u < 4; ++u) {
      const int k = kq * 4 + u;
#pragma unroll
      for (int j = 0; j < NCLS; ++j)
        acc[j] = fmaf(hv[u], Ws[k * NCLS + j], acc[j]);
    }
  }
#pragma unroll
  for (int q = 0; q < 10; ++q) {
    X0b[node * 10 + q] = make_ushort4(f2bf(acc[q * 4]), f2bf(acc[q * 4 + 1]),
                                      f2bf(acc[q * 4 + 2]), f2bf(acc[q * 4 + 3]));
  }
}

// ---------------------------------------------------------------------------
// P1: per-chunk bucket histogram (LDS atomics, coalesced dump)
// ---------------------------------------------------------------------------
__global__ __launch_bounds__(256) void p1_count(const int* __restrict__ row,
                                                int* __restrict__ hist) {
  __shared__ int h[NB2];
  const int tid = threadIdx.x, blk = blockIdx.x;
  for (int i = tid; i < NB2; i += 256) h[i] = 0;
  __syncthreads();
  const int e0 = blk * CHK;
#pragma unroll
  for (int k = 0; k < EPT; ++k) {
    int e = e0 + k * 256 + tid;
    if (e < NE) atomicAdd(&h[row[e] / RPB2], 1);
  }
  __syncthreads();
  for (int i = tid; i < NB2; i += 256) hist[blk * NB2 + i] = h[i];
}

// ---------------------------------------------------------------------------
// P2 hierarchical scan over flat order f = b*NCH + blk (reads hist[blk][b]).
// ---------------------------------------------------------------------------
__global__ __launch_bounds__(1024) void p2a_scan(const int* __restrict__ hist,
                                                 int* __restrict__ base,
                                                 int* __restrict__ bsum) {
  __shared__ int sm[1024];
  const int t = threadIdx.x;
  const int f = blockIdx.x * 1024 + t;
  const int b = f / NCH, blk = f - b * NCH;
  const int v = hist[blk * NB2 + b];
  sm[t] = v;
  __syncthreads();
  for (int off = 1; off < 1024; off <<= 1) {
    int u = (t >= off) ? sm[t - off] : 0;
    __syncthreads();
    sm[t] += u;
    __syncthreads();
  }
  base[f] = sm[t] - v;
  if (t == 1023) bsum[blockIdx.x] = sm[t];
}

__global__ __launch_bounds__(512) void p2b_scan(const int* __restrict__ bsum,
                                                int* __restrict__ boff) {
  __shared__ int sm[512];
  const int t = threadIdx.x;
  const int v = (t < NSB) ? bsum[t] : 0;
  sm[t] = v;
  __syncthreads();
  for (int off = 1; off < 512; off <<= 1) {
    int u = (t >= off) ? sm[t - off] : 0;
    __syncthreads();
    sm[t] += u;
    __syncthreads();
  }
  if (t < NSB) boff[t] = sm[t] - v;
}

__global__ __launch_bounds__(1024) void p2c_add(int* __restrict__ base,
                                                const int* __restrict__ boff) {
  const int f = blockIdx.x * 1024 + threadIdx.x;
  base[f] += boff[blockIdx.x];
}

// ---------------------------------------------------------------------------
// P3: partition into 512 buckets; block-private contiguous global writes.
// staged.x = (col<<8) | row_local;  staged.y = ev bits
// ---------------------------------------------------------------------------
__global__ __launch_bounds__(256) void p3_scatter(
    const int* __restrict__ row, const int* __restrict__ col,
    const float* __restrict__ ev, const int* __restrict__ base,
    int2* __restrict__ staged) {
  __shared__ int h[NB2], lscan[NB2], lcur[NB2], gbase[NB2];
  __shared__ int tmp[256];
  __shared__ int2 pay[CHK];
  __shared__ unsigned short binof[CHK];
  const int tid = threadIdx.x, blk = blockIdx.x;
  for (int i = tid; i < NB2; i += 256) { h[i] = 0; lcur[i] = 0; }
  __syncthreads();
  const int e0 = blk * CHK;
  const int n = (NE - e0 < CHK) ? (NE - e0) : CHK;
  int eb[EPT], em[EPT], ee[EPT];
#pragma unroll
  for (int k = 0; k < EPT; ++k) {
    int e = e0 + k * 256 + tid;
    if (e < NE) {
      int r = row[e];
      int b = r / RPB2;
      eb[k] = b;
      em[k] = (col[e] << 8) | (r - b * RPB2);
      ee[k] = __float_as_int(ev[e]);
      atomicAdd(&h[b], 1);
    } else {
      eb[k] = -1;
    }
  }
  __syncthreads();
  int a = h[2 * tid], c = h[2 * tid + 1];
  tmp[tid] = a + c;
  __syncthreads();
  for (int off = 1; off < 256; off <<= 1) {
    int v = (tid >= off) ? tmp[tid - off] : 0;
    __syncthreads();
    tmp[tid] += v;
    __syncthreads();
  }
  int excl = tmp[tid] - (a + c);
  lscan[2 * tid] = excl;
  lscan[2 * tid + 1] = excl + a;
  gbase[2 * tid] = base[(2 * tid) * NCH + blk];
  gbase[2 * tid + 1] = base[(2 * tid + 1) * NCH + blk];
  __syncthreads();
#pragma unroll
  for (int k = 0; k < EPT; ++k) {
    if (eb[k] >= 0) {
      int b = eb[k];
      int p = lscan[b] + atomicAdd(&lcur[b], 1);
      pay[p] = make_int2(em[k], ee[k]);
      binof[p] = (unsigned short)b;
    }
  }
  __syncthreads();
  for (int j = tid; j < n; j += 256) {
    int b = binof[j];
    staged[gbase[b] + (j - lscan[b])] = pay[j];
  }
}

// ---------------------------------------------------------------------------
// P4: per-bucket reorder by row in LDS -> final CSR segment + rp (derived)
// ---------------------------------------------------------------------------
__global__ __launch_bounds__(256) void p4_emit(
    const int* __restrict__ base, const int2* __restrict__ staged,
    int2* __restrict__ edges, int* __restrict__ rp) {
  __shared__ int h[256], lscan[256], lcur[256];
  __shared__ int tmp[128];
  __shared__ int2 pay[ECAP];
  const int b = blockIdx.x, tid = threadIdx.x;
  const int s0 = base[b * NCH];
  const int s1 = (b == NB2 - 1) ? NE : base[(b + 1) * NCH];
  const int cnt = s1 - s0;
  h[tid] = 0;
  lcur[tid] = 0;
  __syncthreads();
  for (int j = tid; j < cnt; j += 256) atomicAdd(&h[staged[s0 + j].x & 255], 1);
  __syncthreads();
  if (tid < 128) tmp[tid] = h[2 * tid] + h[2 * tid + 1];
  __syncthreads();
  for (int off = 1; off < 128; off <<= 1) {
    int v = (tid < 128 && tid >= off) ? tmp[tid - off] : 0;
    __syncthreads();
    if (tid < 128) tmp[tid] += v;
    __syncthreads();
  }
  if (tid < 128) {
    int a = h[2 * tid];
    int excl = tmp[tid] - (a + h[2 * tid + 1]);
    lscan[2 * tid] = excl;
    lscan[2 * tid + 1] = excl + a;
  }
  __syncthreads();
  if (cnt <= ECAP) {
    for (int j = tid; j < cnt; j += 256) {
      int2 ed = staged[s0 + j];
      int rl = ed.x & 255;
      int p = lscan[rl] + atomicAdd(&lcur[rl], 1);
      pay[p] = make_int2((int)((unsigned)ed.x >> 8), ed.y);
    }
    __syncthreads();
    for (int j = tid; j < cnt; j += 256) edges[s0 + j] = pay[j];
  } else {
    for (int j = tid; j < cnt; j += 256) {
      int2 ed = staged[s0 + j];
      int rl = ed.x & 255;
      int p = lscan[rl] + atomicAdd(&lcur[rl], 1);
      edges[s0 + p] = make_int2((int)((unsigned)ed.x >> 8), ed.y);
    }
  }
  if (tid < RPB2) {
    int r = b * RPB2 + tid;
    if (r <= NN) rp[r] = s0 + lscan[tid];
  }
}

// ---------------------------------------------------------------------------
// Fused propagation (10 iterations) + log_softmax, cooperative launch.
// x_out = 0.9*(A x_in) + 0.1*h, all bf16 payloads, fp32 accumulate.
// TPN=5 threads/node, each owns 8 classes (one 16 B uint4 of packed bf16).
// Edge loads are NON-TEMPORAL: the 25.6 MB/iter edge stream must not evict
// the 8 MB x array from the per-XCD L2s (gathers are the reuse target).
// ---------------------------------------------------------------------------
#define FMA8(v, xb)                                              \
  a0 = fmaf(v, blo(xb.x), a0); a1 = fmaf(v, bhi(xb.x), a1);      \
  a2 = fmaf(v, blo(xb.y), a2); a3 = fmaf(v, bhi(xb.y), a3);      \
  a4 = fmaf(v, blo(xb.z), a4); a5 = fmaf(v, bhi(xb.z), a5);      \
  a6 = fmaf(v, blo(xb.w), a6); a7 = fmaf(v, bhi(xb.w), a7);

__global__ __launch_bounds__(256, 4) void prop_fused(
    const uint4* __restrict__ x0, uint4* __restrict__ xa,
    uint4* __restrict__ xb, const int2* __restrict__ edges,
    const int* __restrict__ rp, float* __restrict__ out) {
  cg::grid_group grid = cg::this_grid();
  const int gsize = gridDim.x * 256;
  const int gtid = blockIdx.x * 256 + threadIdx.x;
  const uint4* in = x0;
  const v4i* edges2 = (const v4i*)edges;

  for (int it = 0; it < 10; ++it) {
    uint4* o = (it & 1) ? xb : xa;
    for (int t = gtid; t < NN * TPN; t += gsize) {
      const int node = t / TPN;
      const int g = t - node * TPN;  // class-group 0..4 (classes 8g..8g+7)
      const int e0 = rp[node], e1 = rp[node + 1];
      float a0 = 0.f, a1 = 0.f, a2 = 0.f, a3 = 0.f;
      float a4 = 0.f, a5 = 0.f, a6 = 0.f, a7 = 0.f;
      int e = e0;
      if ((e & 1) && e < e1) {  // align to even for 16 B edge-pair loads
        v2i ed = __builtin_nontemporal_load((const v2i*)(edges + e));
        float v = __int_as_float(ed[1]);
        uint4 xv = in[ed[0] * TPN + g];
        FMA8(v, xv);
        ++e;
      }
      while (e + 2 <= e1) {
        v4i ep = __builtin_nontemporal_load(edges2 + (e >> 1));
        float v0 = __int_as_float(ep[1]);
        float v1 = __int_as_float(ep[3]);
        uint4 xv0 = in[ep[0] * TPN + g];
        uint4 xv1 = in[ep[2] * TPN + g];
        FMA8(v0, xv0);
        FMA8(v1, xv1);
        e += 2;
      }
      if (e < e1) {
        v2i ed = __builtin_nontemporal_load((const v2i*)(edges + e));
        float v = __int_as_float(ed[1]);
        uint4 xv = in[ed[0] * TPN + g];
        FMA8(v, xv);
      }
      uint4 hh = x0[t];  // t == node*TPN + g
      uint4 r;
      r.x = pk(fmaf(0.9f, a0, 0.1f * blo(hh.x)),
               fmaf(0.9f, a1, 0.1f * bhi(hh.x)));
      r.y = pk(fmaf(0.9f, a2, 0.1f * blo(hh.y)),
               fmaf(0.9f, a3, 0.1f * bhi(hh.y)));
      r.z = pk(fmaf(0.9f, a4, 0.1f * blo(hh.z)),
               fmaf(0.9f, a5, 0.1f * bhi(hh.z)));
      r.w = pk(fmaf(0.9f, a6, 0.1f * blo(hh.w)),
               fmaf(0.9f, a7, 0.1f * bhi(hh.w)));
      o[t] = r;
    }
    grid.sync();  // execution barrier + agent-scope fence (cross-XCD L2)
    in = o;
  }

  // log_softmax over 40 classes (bf16 in, fp32 out)
  const ushort4* X = (const ushort4*)in;
  for (int node = gtid; node < NN; node += gsize) {
    float v[NCLS];
#pragma unroll
    for (int q = 0; q < 10; ++q) {
      ushort4 a = X[node * 10 + q];
      v[q * 4] = bf2f(a.x);
      v[q * 4 + 1] = bf2f(a.y);
      v[q * 4 + 2] = bf2f(a.z);
      v[q * 4 + 3] = bf2f(a.w);
    }
    float m = v[0];
#pragma unroll
    for (int j = 1; j < NCLS; ++j) m = fmaxf(m, v[j]);
    float s = 0.f;
#pragma unroll
    for (int j = 0; j < NCLS; ++j) s += expf(v[j] - m);
    const float l = m + logf(s);
    float4* o4 = (float4*)(out + (long)node * NCLS);
#pragma unroll
    for (int q = 0; q < 10; ++q)
      o4[q] = make_float4(v[q * 4] - l, v[q * 4 + 1] - l, v[q * 4 + 2] - l,
                          v[q * 4 + 3] - l);
  }
}

// ---------------------------------------------------------------------------
// Launch
// ---------------------------------------------------------------------------
extern "C" void kernel_launch(void* const* d_in, const int* in_sizes, int n_in,
                              void* d_out, int out_size, void* d_ws,
                              size_t ws_size, hipStream_t stream) {
  const float* F = (const float*)d_in[0];
  const int* EI = (const int*)d_in[1];
  const float* EV = (const float*)d_in[2];
  const float* W1 = (const float*)d_in[3];
  const float* b1 = (const float*)d_in[4];
  const float* W2 = (const float*)d_in[5];
  const float* b2 = (const float*)d_in[6];
  float* out = (float*)d_out;
  char* ws = (char*)d_ws;

  // ws layout, phase-aliased:
  //   build:  STAGED [0,25.6M)  HIST@42M  BASE@43.7M  BSUM/BOFF@45.4M
  //           EDG [48M,73.6M)  RP@73.6M
  //   gemms:  H [16M,41.6M)  X0b@76M (bf16)
  //   prop :  X0b (=h AND x_0, bf16)  XAb/XBb bf16 @84/92M  EDG, RP
  int2* STAGED = (int2*)(ws + 0);
  float* H = (float*)(ws + 16000000);
  int* HIST = (int*)(ws + 42000000);
  int* BASE = (int*)(ws + 43700000);
  int* BSUM = (int*)(ws + 45400000);
  int* BOFF = (int*)(ws + 45402048);
  int2* EDG = (int2*)(ws + 48000000);
  int* RP = (int*)(ws + 73600000);
  uint4* X0b = (uint4*)(ws + 76000000);  // NN*40 bf16 = 8 MB
  uint4* XAb = (uint4*)(ws + 84000000);
  uint4* XBb = (uint4*)(ws + 92000000);  // ends at 100 MB

  const int* ROW = EI;       // edge_index[0]
  const int* COL = EI + NE;  // edge_index[1]

  // --- CSR build ---
  p1_count<<<NCH, 256, 0, stream>>>(ROW, HIST);
  p2a_scan<<<NSB, 1024, 0, stream>>>(HIST, BASE, BSUM);
  p2b_scan<<<1, 512, 0, stream>>>(BSUM, BOFF);
  p2c_add<<<NSB, 1024, 0, stream>>>(BASE, BOFF);
  p3_scatter<<<NCH, 256, 0, stream>>>(ROW, COL, EV, BASE, STAGED);
  p4_emit<<<NB2, 256, 0, stream>>>(BASE, STAGED, EDG, RP);

  // --- MLP ---
  gemm1_kernel<<<(NN + 63) / 64, 256, 0, stream>>>(F, W1, b1, H);
  gemm2_kernel<<<(NN + 255) / 256, 256, 0, stream>>>(H, W2, b2,
                                                     (ushort4*)X0b);

  // --- propagation + log_softmax: ONE cooperative kernel ---
  {
    const uint4* x0c = X0b;
    void* args[] = {(void*)&x0c, (void*)&XAb, (void*)&XBb,
                    (void*)&EDG, (void*)&RP, (void*)&out};
    hipLaunchCooperativeKernel(reinterpret_cast<void*>(prop_fused),
                               dim3(PGRID), dim3(256), args, 0, stream);
  }
}

// Round 4
// 1163.388 us; speedup vs baseline: 2.2566x; 2.2566x over previous
//
#include <hip/hip_runtime.h>
#include <hip/hip_bf16.h>

// Problem constants (match reference)
#define NN 100000
#define NE 3200000
#define F_IN 512
#define NHID 64
#define NCLS 40

// Radix-partition CSR build params
#define NB2 512   // row buckets
#define RPB2 196  // rows per bucket (512*196 = 100352 >= NN)
#define CHK 4096  // edges per chunk
#define NCH 782   // ceil(NE/CHK)
#define EPT 16    // edges per thread in P3 (CHK/256)
#define ECAP 7168 // emit LDS capacity (mean 6250, sigma 79 -> +11.6 sigma)
#define TOT (NB2 * NCH)  // 400,384 = 391 * 1024 exactly
#define NSB 391   // scan blocks

#define TPN 5     // threads per node in propagation (8 classes each)

// bf16 helpers (exact up-convert; RNE down-convert)
__device__ __forceinline__ float bf2f(unsigned short u) {
  return __uint_as_float((unsigned)u << 16);
}
__device__ __forceinline__ unsigned short f2bf(float f) {
  unsigned u = __float_as_uint(f);
  u += 0x7FFFu + ((u >> 16) & 1u);  // round-to-nearest-even
  return (unsigned short)(u >> 16);
}
// packed-bf16 (uint = 2 classes) helpers
__device__ __forceinline__ float blo(unsigned u) {
  return __uint_as_float(u << 16);
}
__device__ __forceinline__ float bhi(unsigned u) {
  return __uint_as_float(u & 0xffff0000u);
}
__device__ __forceinline__ unsigned pk(float l, float h) {
  return (unsigned)f2bf(l) | ((unsigned)f2bf(h) << 16);
}

// ---------------------------------------------------------------------------
// GEMM1: H[N,64] = relu(F[N,512] @ W1[512,64] + b1)
// ---------------------------------------------------------------------------
__global__ __launch_bounds__(256) void gemm1_kernel(
    const float* __restrict__ F, const float* __restrict__ W1,
    const float* __restrict__ b1, float* __restrict__ H) {
  __shared__ float As[16][68];
  __shared__ float Bs[16][64];
  const int tid = threadIdx.x;
  const int m0 = blockIdx.x * 64;
  const int ty = tid >> 4;
  const int tx = tid & 15;
  const int lrowA = tid >> 2;
  const int lkA = (tid & 3) * 4;
  const int lkB = tid >> 4;
  const int lcolB = (tid & 15) * 4;
  const bool rowok = (m0 + lrowA) < NN;
  const int rclamp = rowok ? (m0 + lrowA) : (NN - 1);
  const float* Fb = F + (long)rclamp * F_IN + lkA;

  float acc[4][4] = {};
  for (int k0 = 0; k0 < F_IN; k0 += 16) {
    float4 fa = *(const float4*)(Fb + k0);
    if (!rowok) fa = make_float4(0.f, 0.f, 0.f, 0.f);
    float4 wb = *(const float4*)(W1 + (long)(k0 + lkB) * NHID + lcolB);
    __syncthreads();
    As[lkA + 0][lrowA] = fa.x;
    As[lkA + 1][lrowA] = fa.y;
    As[lkA + 2][lrowA] = fa.z;
    As[lkA + 3][lrowA] = fa.w;
    *(float4*)&Bs[lkB][lcolB] = wb;
    __syncthreads();
#pragma unroll
    for (int kk = 0; kk < 16; ++kk) {
      float4 a = *(const float4*)&As[kk][ty * 4];
      float4 b = *(const float4*)&Bs[kk][tx * 4];
      float av[4] = {a.x, a.y, a.z, a.w};
      float bv[4] = {b.x, b.y, b.z, b.w};
#pragma unroll
      for (int i = 0; i < 4; ++i)
#pragma unroll
        for (int j = 0; j < 4; ++j) acc[i][j] = fmaf(av[i], bv[j], acc[i][j]);
    }
  }
  float4 bb = *(const float4*)(b1 + tx * 4);
  float bv[4] = {bb.x, bb.y, bb.z, bb.w};
#pragma unroll
  for (int i = 0; i < 4; ++i) {
    int r = m0 + ty * 4 + i;
    if (r < NN) {
      float4 o;
      o.x = fmaxf(acc[i][0] + bv[0], 0.f);
      o.y = fmaxf(acc[i][1] + bv[1], 0.f);
      o.z = fmaxf(acc[i][2] + bv[2], 0.f);
      o.w = fmaxf(acc[i][3] + bv[3], 0.f);
      *(float4*)(H + (long)r * NHID + tx * 4) = o;
    }
  }
}

// ---------------------------------------------------------------------------
// GEMM2: X0b (bf16) = H @ W2 + b2.  (teleport term h consumed in bf16)
// ---------------------------------------------------------------------------
__global__ __launch_bounds__(256) void gemm2_kernel(
    const float* __restrict__ H, const float* __restrict__ W2,
    const float* __restrict__ b2, ushort4* __restrict__ X0b) {
  __shared__ float Ws[NHID * NCLS];
  __shared__ float bs[NCLS];
  const int tid = threadIdx.x;
  for (int i = tid; i < NHID * NCLS; i += 256) Ws[i] = W2[i];
  if (tid < NCLS) bs[tid] = b2[tid];
  __syncthreads();
  const int node = blockIdx.x * 256 + tid;
  if (node >= NN) return;
  float acc[NCLS];
#pragma unroll
  for (int j = 0; j < NCLS; ++j) acc[j] = bs[j];
  const float4* h4 = (const float4*)(H + (long)node * NHID);
#pragma unroll
  for (int kq = 0; kq < 16; ++kq) {
    float4 h = h4[kq];
    float hv[4] = {h.x, h.y, h.z, h.w};
#pragma unroll
    for (int u = 0; u < 4; ++u) {
      const int k = kq * 4 + u;
#pragma unroll
      for (int j = 0; j < NCLS; ++j)
        acc[j] = fmaf(hv[u], Ws[k * NCLS + j], acc[j]);
    }
  }
#pragma unroll
  for (int q = 0; q < 10; ++q) {
    X0b[node * 10 + q] = make_ushort4(f2bf(acc[q * 4]), f2bf(acc[q * 4 + 1]),
                                      f2bf(acc[q * 4 + 2]), f2bf(acc[q * 4 + 3]));
  }
}

// ---------------------------------------------------------------------------
// P1: per-chunk bucket histogram (LDS atomics, coalesced dump)
// ---------------------------------------------------------------------------
__global__ __launch_bounds__(256) void p1_count(const int* __restrict__ row,
                                                int* __restrict__ hist) {
  __shared__ int h[NB2];
  const int tid = threadIdx.x, blk = blockIdx.x;
  for (int i = tid; i < NB2; i += 256) h[i] = 0;
  __syncthreads();
  const int e0 = blk * CHK;
#pragma unroll
  for (int k = 0; k < EPT; ++k) {
    int e = e0 + k * 256 + tid;
    if (e < NE) atomicAdd(&h[row[e] / RPB2], 1);
  }
  __syncthreads();
  for (int i = tid; i < NB2; i += 256) hist[blk * NB2 + i] = h[i];
}

// ---------------------------------------------------------------------------
// P2 hierarchical scan over flat order f = b*NCH + blk (reads hist[blk][b]).
// ---------------------------------------------------------------------------
__global__ __launch_bounds__(1024) void p2a_scan(const int* __restrict__ hist,
                                                 int* __restrict__ base,
                                                 int* __restrict__ bsum) {
  __shared__ int sm[1024];
  const int t = threadIdx.x;
  const int f = blockIdx.x * 1024 + t;
  const int b = f / NCH, blk = f - b * NCH;
  const int v = hist[blk * NB2 + b];
  sm[t] = v;
  __syncthreads();
  for (int off = 1; off < 1024; off <<= 1) {
    int u = (t >= off) ? sm[t - off] : 0;
    __syncthreads();
    sm[t] += u;
    __syncthreads();
  }
  base[f] = sm[t] - v;
  if (t == 1023) bsum[blockIdx.x] = sm[t];
}

__global__ __launch_bounds__(512) void p2b_scan(const int* __restrict__ bsum,
                                                int* __restrict__ boff) {
  __shared__ int sm[512];
  const int t = threadIdx.x;
  const int v = (t < NSB) ? bsum[t] : 0;
  sm[t] = v;
  __syncthreads();
  for (int off = 1; off < 512; off <<= 1) {
    int u = (t >= off) ? sm[t - off] : 0;
    __syncthreads();
    sm[t] += u;
    __syncthreads();
  }
  if (t < NSB) boff[t] = sm[t] - v;
}

__global__ __launch_bounds__(1024) void p2c_add(int* __restrict__ base,
                                                const int* __restrict__ boff) {
  const int f = blockIdx.x * 1024 + threadIdx.x;
  base[f] += boff[blockIdx.x];
}

// ---------------------------------------------------------------------------
// P3: partition into 512 buckets; block-private contiguous global writes.
// staged.x = (col<<8) | row_local;  staged.y = ev bits
// ---------------------------------------------------------------------------
__global__ __launch_bounds__(256) void p3_scatter(
    const int* __restrict__ row, const int* __restrict__ col,
    const float* __restrict__ ev, const int* __restrict__ base,
    int2* __restrict__ staged) {
  __shared__ int h[NB2], lscan[NB2], lcur[NB2], gbase[NB2];
  __shared__ int tmp[256];
  __shared__ int2 pay[CHK];
  __shared__ unsigned short binof[CHK];
  const int tid = threadIdx.x, blk = blockIdx.x;
  for (int i = tid; i < NB2; i += 256) { h[i] = 0; lcur[i] = 0; }
  __syncthreads();
  const int e0 = blk * CHK;
  const int n = (NE - e0 < CHK) ? (NE - e0) : CHK;
  int eb[EPT], em[EPT], ee[EPT];
#pragma unroll
  for (int k = 0; k < EPT; ++k) {
    int e = e0 + k * 256 + tid;
    if (e < NE) {
      int r = row[e];
      int b = r / RPB2;
      eb[k] = b;
      em[k] = (col[e] << 8) | (r - b * RPB2);
      ee[k] = __float_as_int(ev[e]);
      atomicAdd(&h[b], 1);
    } else {
      eb[k] = -1;
    }
  }
  __syncthreads();
  int a = h[2 * tid], c = h[2 * tid + 1];
  tmp[tid] = a + c;
  __syncthreads();
  for (int off = 1; off < 256; off <<= 1) {
    int v = (tid >= off) ? tmp[tid - off] : 0;
    __syncthreads();
    tmp[tid] += v;
    __syncthreads();
  }
  int excl = tmp[tid] - (a + c);
  lscan[2 * tid] = excl;
  lscan[2 * tid + 1] = excl + a;
  gbase[2 * tid] = base[(2 * tid) * NCH + blk];
  gbase[2 * tid + 1] = base[(2 * tid + 1) * NCH + blk];
  __syncthreads();
#pragma unroll
  for (int k = 0; k < EPT; ++k) {
    if (eb[k] >= 0) {
      int b = eb[k];
      int p = lscan[b] + atomicAdd(&lcur[b], 1);
      pay[p] = make_int2(em[k], ee[k]);
      binof[p] = (unsigned short)b;
    }
  }
  __syncthreads();
  for (int j = tid; j < n; j += 256) {
    int b = binof[j];
    staged[gbase[b] + (j - lscan[b])] = pay[j];
  }
}

// ---------------------------------------------------------------------------
// P4: per-bucket reorder by row in LDS, then sort each row's edges by column
// (ascending) so propagation gathers walk x in a moving window that fits L2.
// Emits final CSR segment + rp (derived).
// ---------------------------------------------------------------------------
__global__ __launch_bounds__(256) void p4_emit(
    const int* __restrict__ base, const int2* __restrict__ staged,
    int2* __restrict__ edges, int* __restrict__ rp) {
  __shared__ int h[256], lscan[256], lcur[256];
  __shared__ int tmp[128];
  __shared__ int2 pay[ECAP];
  const int b = blockIdx.x, tid = threadIdx.x;
  const int s0 = base[b * NCH];
  const int s1 = (b == NB2 - 1) ? NE : base[(b + 1) * NCH];
  const int cnt = s1 - s0;
  h[tid] = 0;
  lcur[tid] = 0;
  __syncthreads();
  for (int j = tid; j < cnt; j += 256) atomicAdd(&h[staged[s0 + j].x & 255], 1);
  __syncthreads();
  if (tid < 128) tmp[tid] = h[2 * tid] + h[2 * tid + 1];
  __syncthreads();
  for (int off = 1; off < 128; off <<= 1) {
    int v = (tid < 128 && tid >= off) ? tmp[tid - off] : 0;
    __syncthreads();
    if (tid < 128) tmp[tid] += v;
    __syncthreads();
  }
  if (tid < 128) {
    int a = h[2 * tid];
    int excl = tmp[tid] - (a + h[2 * tid + 1]);
    lscan[2 * tid] = excl;
    lscan[2 * tid + 1] = excl + a;
  }
  __syncthreads();
  if (cnt <= ECAP) {
    for (int j = tid; j < cnt; j += 256) {
      int2 ed = staged[s0 + j];
      int rl = ed.x & 255;
      int p = lscan[rl] + atomicAdd(&lcur[rl], 1);
      pay[p] = make_int2((int)((unsigned)ed.x >> 8), ed.y);
    }
    __syncthreads();
    // per-row insertion sort by column (one thread per row, in LDS)
    if (tid < RPB2) {
      const int s = lscan[tid];
      const int n2 = h[tid];
      for (int i = 1; i < n2; ++i) {
        int2 key = pay[s + i];
        int j = i - 1;
        while (j >= 0 && (unsigned)pay[s + j].x > (unsigned)key.x) {
          pay[s + j + 1] = pay[s + j];
          --j;
        }
        pay[s + j + 1] = key;
      }
    }
    __syncthreads();
    for (int j = tid; j < cnt; j += 256) edges[s0 + j] = pay[j];
  } else {
    for (int j = tid; j < cnt; j += 256) {
      int2 ed = staged[s0 + j];
      int rl = ed.x & 255;
      int p = lscan[rl] + atomicAdd(&lcur[rl], 1);
      edges[s0 + p] = make_int2((int)((unsigned)ed.x >> 8), ed.y);
    }
  }
  if (tid < RPB2) {
    int r = b * RPB2 + tid;
    if (r <= NN) rp[r] = s0 + lscan[tid];
  }
}

// ---------------------------------------------------------------------------
// Propagation (bf16 x): x_out = 0.9*(A x_in) + 0.1*h.
// TPN=5 threads/node, each owns 8 classes (one 16 B uint4 of packed bf16).
// Edges within a row are column-sorted -> gathers sweep x in a moving
// window (~1-2 MB) that stays resident in the 4 MiB per-XCD L2.
// ---------------------------------------------------------------------------
#define FMA8(v, xb)                                              \
  a0 = fmaf(v, blo(xb.x), a0); a1 = fmaf(v, bhi(xb.x), a1);      \
  a2 = fmaf(v, blo(xb.y), a2); a3 = fmaf(v, bhi(xb.y), a3);      \
  a4 = fmaf(v, blo(xb.z), a4); a5 = fmaf(v, bhi(xb.z), a5);      \
  a6 = fmaf(v, blo(xb.w), a6); a7 = fmaf(v, bhi(xb.w), a7);

__global__ __launch_bounds__(256) void prop_kernel_bf16(
    const uint4* __restrict__ xin, uint4* __restrict__ xout,
    const uint4* __restrict__ hb, const int2* __restrict__ edges,
    const int* __restrict__ rp) {
  const int t = blockIdx.x * 256 + threadIdx.x;
  const int node = t / TPN;
  if (node >= NN) return;
  const int g = t - node * TPN;  // class-group 0..4 (classes 8g..8g+7)
  const int e0 = rp[node], e1 = rp[node + 1];
  float a0 = 0.f, a1 = 0.f, a2 = 0.f, a3 = 0.f;
  float a4 = 0.f, a5 = 0.f, a6 = 0.f, a7 = 0.f;
  int e = e0;
  // prologue: align e to even for int4 edge-pair loads
  if ((e & 1) && e < e1) {
    int2 ed = edges[e];
    float v = __int_as_float(ed.y);
    uint4 xb = xin[ed.x * TPN + g];
    FMA8(v, xb);
    ++e;
  }
  const int4* edges2 = (const int4*)edges;
  while (e + 2 <= e1) {
    int4 ep = edges2[e >> 1];
    float v0 = __int_as_float(ep.y);
    float v1 = __int_as_float(ep.w);
    uint4 xb0 = xin[ep.x * TPN + g];
    uint4 xb1 = xin[ep.z * TPN + g];
    FMA8(v0, xb0);
    FMA8(v1, xb1);
    e += 2;
  }
  if (e < e1) {
    int2 ed = edges[e];
    float v = __int_as_float(ed.y);
    uint4 xb = xin[ed.x * TPN + g];
    FMA8(v, xb);
  }
  uint4 hh = hb[node * TPN + g];
  uint4 r;
  r.x = pk(fmaf(0.9f, a0, 0.1f * blo(hh.x)), fmaf(0.9f, a1, 0.1f * bhi(hh.x)));
  r.y = pk(fmaf(0.9f, a2, 0.1f * blo(hh.y)), fmaf(0.9f, a3, 0.1f * bhi(hh.y)));
  r.z = pk(fmaf(0.9f, a4, 0.1f * blo(hh.z)), fmaf(0.9f, a5, 0.1f * bhi(hh.z)));
  r.w = pk(fmaf(0.9f, a6, 0.1f * blo(hh.w)), fmaf(0.9f, a7, 0.1f * bhi(hh.w)));
  xout[node * TPN + g] = r;
}

// ---------------------------------------------------------------------------
// log_softmax over 40 classes (bf16 in, fp32 out), one thread per node
// ---------------------------------------------------------------------------
__global__ __launch_bounds__(256) void logsm_kernel(
    const ushort4* __restrict__ X, float* __restrict__ out) {
  const int node = blockIdx.x * 256 + threadIdx.x;
  if (node >= NN) return;
  float v[NCLS];
#pragma unroll
  for (int q = 0; q < 10; ++q) {
    ushort4 a = X[node * 10 + q];
    v[q * 4] = bf2f(a.x);
    v[q * 4 + 1] = bf2f(a.y);
    v[q * 4 + 2] = bf2f(a.z);
    v[q * 4 + 3] = bf2f(a.w);
  }
  float m = v[0];
#pragma unroll
  for (int j = 1; j < NCLS; ++j) m = fmaxf(m, v[j]);
  float s = 0.f;
#pragma unroll
  for (int j = 0; j < NCLS; ++j) s += expf(v[j] - m);
  const float l = m + logf(s);
  float4* o4 = (float4*)(out + (long)node * NCLS);
#pragma unroll
  for (int q = 0; q < 10; ++q)
    o4[q] = make_float4(v[q * 4] - l, v[q * 4 + 1] - l, v[q * 4 + 2] - l,
                        v[q * 4 + 3] - l);
}

// ---------------------------------------------------------------------------
// Launch
// ---------------------------------------------------------------------------
extern "C" void kernel_launch(void* const* d_in, const int* in_sizes, int n_in,
                              void* d_out, int out_size, void* d_ws,
                              size_t ws_size, hipStream_t stream) {
  const float* F = (const float*)d_in[0];
  const int* EI = (const int*)d_in[1];
  const float* EV = (const float*)d_in[2];
  const float* W1 = (const float*)d_in[3];
  const float* b1 = (const float*)d_in[4];
  const float* W2 = (const float*)d_in[5];
  const float* b2 = (const float*)d_in[6];
  float* out = (float*)d_out;
  char* ws = (char*)d_ws;

  // ws layout, phase-aliased:
  //   build:  STAGED [0,25.6M)  HIST@42M  BASE@43.7M  BSUM/BOFF@45.4M
  //           EDG [48M,73.6M)  RP@73.6M
  //   gemms:  H [16M,41.6M)  X0b@76M (bf16)
  //   prop :  X0b (=h AND x_0, bf16)  XAb/XBb bf16 @84/92M  EDG, RP
  int2* STAGED = (int2*)(ws + 0);
  float* H = (float*)(ws + 16000000);
  int* HIST = (int*)(ws + 42000000);
  int* BASE = (int*)(ws + 43700000);
  int* BSUM = (int*)(ws + 45400000);
  int* BOFF = (int*)(ws + 45402048);
  int2* EDG = (int2*)(ws + 48000000);
  int* RP = (int*)(ws + 73600000);
  uint4* X0b = (uint4*)(ws + 76000000);  // NN*40 bf16 = 8 MB
  uint4* XAb = (uint4*)(ws + 84000000);
  uint4* XBb = (uint4*)(ws + 92000000);  // ends at 100 MB

  const int* ROW = EI;       // edge_index[0]
  const int* COL = EI + NE;  // edge_index[1]

  // --- CSR build ---
  p1_count<<<NCH, 256, 0, stream>>>(ROW, HIST);
  p2a_scan<<<NSB, 1024, 0, stream>>>(HIST, BASE, BSUM);
  p2b_scan<<<1, 512, 0, stream>>>(BSUM, BOFF);
  p2c_add<<<NSB, 1024, 0, stream>>>(BASE, BOFF);
  p3_scatter<<<NCH, 256, 0, stream>>>(ROW, COL, EV, BASE, STAGED);
  p4_emit<<<NB2, 256, 0, stream>>>(BASE, STAGED, EDG, RP);

  // --- MLP ---
  gemm1_kernel<<<(NN + 63) / 64, 256, 0, stream>>>(F, W1, b1, H);
  gemm2_kernel<<<(NN + 255) / 256, 256, 0, stream>>>(H, W2, b2,
                                                     (ushort4*)X0b);

  // --- propagation (bf16 x, bf16 h) ---
  const int tgrid = (NN * TPN + 255) / 256;
  const uint4* cur_in = X0b;
  uint4* bufs[2] = {XAb, XBb};
  for (int it = 0; it < 10; ++it) {
    uint4* o = bufs[it & 1];
    prop_kernel_bf16<<<tgrid, 256, 0, stream>>>(cur_in, o, X0b, EDG, RP);
    cur_in = o;
  }
  logsm_kernel<<<(NN + 255) / 256, 256, 0, stream>>>((const ushort4*)cur_in,
                                                     out);
}

// Round 5
// 1037.617 us; speedup vs baseline: 2.5302x; 1.1212x over previous
//
#include <hip/hip_runtime.h>
#include <hip/hip_bf16.h>

// Problem constants (match reference)
#define NN 100000
#define NE 3200000
#define F_IN 512
#define NHID 64
#define NCLS 40

// Radix-partition CSR build params
#define NB2 512   // row buckets
#define RPB2 196  // rows per bucket (512*196 = 100352 >= NN)
#define CHK 4096  // edges per chunk
#define NCH 782   // ceil(NE/CHK)
#define EPT 16    // edges per thread in P3 (CHK/256)
#define ECAP 7168 // emit LDS capacity (mean 6250, sigma 79 -> +11.6 sigma)
#define TOT (NB2 * NCH)  // 400,384 = 391 * 1024 exactly
#define NSB 391   // scan blocks

#define TPN 5     // threads per node in propagation (8 classes each)

// P4 combined-key counting sort: key = (row_local<<6) | (col>>11)
#define GCOL 64   // column groups per row (col granularity 2048 nodes)
#define CSH 11
#define NBIN (RPB2 * GCOL)  // 12544 = 256 * 49
#define SEG (NBIN / 256)    // 49 bins per thread in the scan

// bf16 helpers (exact up-convert; RNE down-convert)
__device__ __forceinline__ float bf2f(unsigned short u) {
  return __uint_as_float((unsigned)u << 16);
}
__device__ __forceinline__ unsigned short f2bf(float f) {
  unsigned u = __float_as_uint(f);
  u += 0x7FFFu + ((u >> 16) & 1u);  // round-to-nearest-even
  return (unsigned short)(u >> 16);
}
// packed-bf16 (uint = 2 classes) helpers
__device__ __forceinline__ float blo(unsigned u) {
  return __uint_as_float(u << 16);
}
__device__ __forceinline__ float bhi(unsigned u) {
  return __uint_as_float(u & 0xffff0000u);
}
__device__ __forceinline__ unsigned pk(float l, float h) {
  return (unsigned)f2bf(l) | ((unsigned)f2bf(h) << 16);
}

// ---------------------------------------------------------------------------
// GEMM1: H[N,64] = relu(F[N,512] @ W1[512,64] + b1)
// ---------------------------------------------------------------------------
__global__ __launch_bounds__(256) void gemm1_kernel(
    const float* __restrict__ F, const float* __restrict__ W1,
    const float* __restrict__ b1, float* __restrict__ H) {
  __shared__ float As[16][68];
  __shared__ float Bs[16][64];
  const int tid = threadIdx.x;
  const int m0 = blockIdx.x * 64;
  const int ty = tid >> 4;
  const int tx = tid & 15;
  const int lrowA = tid >> 2;
  const int lkA = (tid & 3) * 4;
  const int lkB = tid >> 4;
  const int lcolB = (tid & 15) * 4;
  const bool rowok = (m0 + lrowA) < NN;
  const int rclamp = rowok ? (m0 + lrowA) : (NN - 1);
  const float* Fb = F + (long)rclamp * F_IN + lkA;

  float acc[4][4] = {};
  for (int k0 = 0; k0 < F_IN; k0 += 16) {
    float4 fa = *(const float4*)(Fb + k0);
    if (!rowok) fa = make_float4(0.f, 0.f, 0.f, 0.f);
    float4 wb = *(const float4*)(W1 + (long)(k0 + lkB) * NHID + lcolB);
    __syncthreads();
    As[lkA + 0][lrowA] = fa.x;
    As[lkA + 1][lrowA] = fa.y;
    As[lkA + 2][lrowA] = fa.z;
    As[lkA + 3][lrowA] = fa.w;
    *(float4*)&Bs[lkB][lcolB] = wb;
    __syncthreads();
#pragma unroll
    for (int kk = 0; kk < 16; ++kk) {
      float4 a = *(const float4*)&As[kk][ty * 4];
      float4 b = *(const float4*)&Bs[kk][tx * 4];
      float av[4] = {a.x, a.y, a.z, a.w};
      float bv[4] = {b.x, b.y, b.z, b.w};
#pragma unroll
      for (int i = 0; i < 4; ++i)
#pragma unroll
        for (int j = 0; j < 4; ++j) acc[i][j] = fmaf(av[i], bv[j], acc[i][j]);
    }
  }
  float4 bb = *(const float4*)(b1 + tx * 4);
  float bv[4] = {bb.x, bb.y, bb.z, bb.w};
#pragma unroll
  for (int i = 0; i < 4; ++i) {
    int r = m0 + ty * 4 + i;
    if (r < NN) {
      float4 o;
      o.x = fmaxf(acc[i][0] + bv[0], 0.f);
      o.y = fmaxf(acc[i][1] + bv[1], 0.f);
      o.z = fmaxf(acc[i][2] + bv[2], 0.f);
      o.w = fmaxf(acc[i][3] + bv[3], 0.f);
      *(float4*)(H + (long)r * NHID + tx * 4) = o;
    }
  }
}

// ---------------------------------------------------------------------------
// GEMM2: X0b (bf16) = H @ W2 + b2.  (teleport term h consumed in bf16)
// ---------------------------------------------------------------------------
__global__ __launch_bounds__(256) void gemm2_kernel(
    const float* __restrict__ H, const float* __restrict__ W2,
    const float* __restrict__ b2, ushort4* __restrict__ X0b) {
  __shared__ float Ws[NHID * NCLS];
  __shared__ float bs[NCLS];
  const int tid = threadIdx.x;
  for (int i = tid; i < NHID * NCLS; i += 256) Ws[i] = W2[i];
  if (tid < NCLS) bs[tid] = b2[tid];
  __syncthreads();
  const int node = blockIdx.x * 256 + tid;
  if (node >= NN) return;
  float acc[NCLS];
#pragma unroll
  for (int j = 0; j < NCLS; ++j) acc[j] = bs[j];
  const float4* h4 = (const float4*)(H + (long)node * NHID);
#pragma unroll
  for (int kq = 0; kq < 16; ++kq) {
    float4 h = h4[kq];
    float hv[4] = {h.x, h.y, h.z, h.w};
#pragma unroll
    for (int u = 0; u < 4; ++u) {
      const int k = kq * 4 + u;
#pragma unroll
      for (int j = 0; j < NCLS; ++j)
        acc[j] = fmaf(hv[u], Ws[k * NCLS + j], acc[j]);
    }
  }
#pragma unroll
  for (int q = 0; q < 10; ++q) {
    X0b[node * 10 + q] = make_ushort4(f2bf(acc[q * 4]), f2bf(acc[q * 4 + 1]),
                                      f2bf(acc[q * 4 + 2]), f2bf(acc[q * 4 + 3]));
  }
}

// ---------------------------------------------------------------------------
// P1: per-chunk bucket histogram (LDS atomics, coalesced dump)
// ---------------------------------------------------------------------------
__global__ __launch_bounds__(256) void p1_count(const int* __restrict__ row,
                                                int* __restrict__ hist) {
  __shared__ int h[NB2];
  const int tid = threadIdx.x, blk = blockIdx.x;
  for (int i = tid; i < NB2; i += 256) h[i] = 0;
  __syncthreads();
  const int e0 = blk * CHK;
#pragma unroll
  for (int k = 0; k < EPT; ++k) {
    int e = e0 + k * 256 + tid;
    if (e < NE) atomicAdd(&h[row[e] / RPB2], 1);
  }
  __syncthreads();
  for (int i = tid; i < NB2; i += 256) hist[blk * NB2 + i] = h[i];
}

// ---------------------------------------------------------------------------
// P2 hierarchical scan over flat order f = b*NCH + blk (reads hist[blk][b]).
// ---------------------------------------------------------------------------
__global__ __launch_bounds__(1024) void p2a_scan(const int* __restrict__ hist,
                                                 int* __restrict__ base,
                                                 int* __restrict__ bsum) {
  __shared__ int sm[1024];
  const int t = threadIdx.x;
  const int f = blockIdx.x * 1024 + t;
  const int b = f / NCH, blk = f - b * NCH;
  const int v = hist[blk * NB2 + b];
  sm[t] = v;
  __syncthreads();
  for (int off = 1; off < 1024; off <<= 1) {
    int u = (t >= off) ? sm[t - off] : 0;
    __syncthreads();
    sm[t] += u;
    __syncthreads();
  }
  base[f] = sm[t] - v;
  if (t == 1023) bsum[blockIdx.x] = sm[t];
}

__global__ __launch_bounds__(512) void p2b_scan(const int* __restrict__ bsum,
                                                int* __restrict__ boff) {
  __shared__ int sm[512];
  const int t = threadIdx.x;
  const int v = (t < NSB) ? bsum[t] : 0;
  sm[t] = v;
  __syncthreads();
  for (int off = 1; off < 512; off <<= 1) {
    int u = (t >= off) ? sm[t - off] : 0;
    __syncthreads();
    sm[t] += u;
    __syncthreads();
  }
  if (t < NSB) boff[t] = sm[t] - v;
}

__global__ __launch_bounds__(1024) void p2c_add(int* __restrict__ base,
                                                const int* __restrict__ boff) {
  const int f = blockIdx.x * 1024 + threadIdx.x;
  base[f] += boff[blockIdx.x];
}

// ---------------------------------------------------------------------------
// P3: partition into 512 buckets; block-private contiguous global writes.
// staged.x = (col<<8) | row_local;  staged.y = ev bits
// ---------------------------------------------------------------------------
__global__ __launch_bounds__(256) void p3_scatter(
    const int* __restrict__ row, const int* __restrict__ col,
    const float* __restrict__ ev, const int* __restrict__ base,
    int2* __restrict__ staged) {
  __shared__ int h[NB2], lscan[NB2], lcur[NB2], gbase[NB2];
  __shared__ int tmp[256];
  __shared__ int2 pay[CHK];
  __shared__ unsigned short binof[CHK];
  const int tid = threadIdx.x, blk = blockIdx.x;
  for (int i = tid; i < NB2; i += 256) { h[i] = 0; lcur[i] = 0; }
  __syncthreads();
  const int e0 = blk * CHK;
  const int n = (NE - e0 < CHK) ? (NE - e0) : CHK;
  int eb[EPT], em[EPT], ee[EPT];
#pragma unroll
  for (int k = 0; k < EPT; ++k) {
    int e = e0 + k * 256 + tid;
    if (e < NE) {
      int r = row[e];
      int b = r / RPB2;
      eb[k] = b;
      em[k] = (col[e] << 8) | (r - b * RPB2);
      ee[k] = __float_as_int(ev[e]);
      atomicAdd(&h[b], 1);
    } else {
      eb[k] = -1;
    }
  }
  __syncthreads();
  int a = h[2 * tid], c = h[2 * tid + 1];
  tmp[tid] = a + c;
  __syncthreads();
  for (int off = 1; off < 256; off <<= 1) {
    int v = (tid >= off) ? tmp[tid - off] : 0;
    __syncthreads();
    tmp[tid] += v;
    __syncthreads();
  }
  int excl = tmp[tid] - (a + c);
  lscan[2 * tid] = excl;
  lscan[2 * tid + 1] = excl + a;
  gbase[2 * tid] = base[(2 * tid) * NCH + blk];
  gbase[2 * tid + 1] = base[(2 * tid + 1) * NCH + blk];
  __syncthreads();
#pragma unroll
  for (int k = 0; k < EPT; ++k) {
    if (eb[k] >= 0) {
      int b = eb[k];
      int p = lscan[b] + atomicAdd(&lcur[b], 1);
      pay[p] = make_int2(em[k], ee[k]);
      binof[p] = (unsigned short)b;
    }
  }
  __syncthreads();
  for (int j = tid; j < n; j += 256) {
    int b = binof[j];
    staged[gbase[b] + (j - lscan[b])] = pay[j];
  }
}

// ---------------------------------------------------------------------------
// P4: parallel counting sort by combined key (row_local, col>>11) in LDS.
// Gives exact row grouping (CSR) + coarse ascending column order within each
// row (2048-node granularity) -> prop gathers sweep x in an L2-resident
// moving window. Fully data-parallel: histogram + segmented scan + scatter.
// ---------------------------------------------------------------------------
__global__ __launch_bounds__(256) void p4_emit(
    const int* __restrict__ base, const int2* __restrict__ staged,
    int2* __restrict__ edges, int* __restrict__ rp) {
  __shared__ int bh[NBIN];      // 12544 bins: histogram -> starts -> cursors
  __shared__ int tsum[256];
  __shared__ int2 pay[ECAP];
  const int b = blockIdx.x, tid = threadIdx.x;
  const int s0 = base[b * NCH];
  const int s1 = (b == NB2 - 1) ? NE : base[(b + 1) * NCH];
  const int cnt = s1 - s0;
  for (int i = tid; i < NBIN; i += 256) bh[i] = 0;
  __syncthreads();
  // histogram over combined key
  for (int j = tid; j < cnt; j += 256) {
    int ex = staged[s0 + j].x;
    int rl = ex & 255;
    unsigned col = (unsigned)ex >> 8;
    atomicAdd(&bh[(rl << 6) | (col >> CSH)], 1);
  }
  __syncthreads();
  // exclusive scan over 12544 bins: 49 serial bins/thread + block scan
  int s = 0;
#pragma unroll
  for (int i = 0; i < SEG; ++i) {
    int v = bh[tid * SEG + i];
    bh[tid * SEG + i] = s;
    s += v;
  }
  tsum[tid] = s;
  __syncthreads();
  for (int off = 1; off < 256; off <<= 1) {
    int u = (tid >= off) ? tsum[tid - off] : 0;
    __syncthreads();
    tsum[tid] += u;
    __syncthreads();
  }
  const int add = (tid > 0) ? tsum[tid - 1] : 0;
#pragma unroll
  for (int i = 0; i < SEG; ++i) bh[tid * SEG + i] += add;
  __syncthreads();
  // rp from row-bin starts (before scatter mutates the cursors)
  if (tid < RPB2) {
    int r = b * RPB2 + tid;
    if (r <= NN) rp[r] = s0 + bh[tid << 6];
  }
  __syncthreads();
  // scatter via per-bin cursors
  if (cnt <= ECAP) {
    for (int j = tid; j < cnt; j += 256) {
      int2 ed = staged[s0 + j];
      int rl = ed.x & 255;
      unsigned col = (unsigned)ed.x >> 8;
      int p = atomicAdd(&bh[(rl << 6) | (col >> CSH)], 1);
      pay[p] = make_int2((int)col, ed.y);
    }
    __syncthreads();
    for (int j = tid; j < cnt; j += 256) edges[s0 + j] = pay[j];
  } else {
    for (int j = tid; j < cnt; j += 256) {
      int2 ed = staged[s0 + j];
      int rl = ed.x & 255;
      unsigned col = (unsigned)ed.x >> 8;
      int p = atomicAdd(&bh[(rl << 6) | (col >> CSH)], 1);
      edges[s0 + p] = make_int2((int)col, ed.y);
    }
  }
}

// ---------------------------------------------------------------------------
// Propagation (bf16 x): x_out = 0.9*(A x_in) + 0.1*h.
// TPN=5 threads/node, each owns 8 classes (one 16 B uint4 of packed bf16).
// Edges within a row are coarse column-sorted -> gathers sweep x in a moving
// window that stays resident in the 4 MiB per-XCD L2.
// ---------------------------------------------------------------------------
#define FMA8(v, xb)                                              \
  a0 = fmaf(v, blo(xb.x), a0); a1 = fmaf(v, bhi(xb.x), a1);      \
  a2 = fmaf(v, blo(xb.y), a2); a3 = fmaf(v, bhi(xb.y), a3);      \
  a4 = fmaf(v, blo(xb.z), a4); a5 = fmaf(v, bhi(xb.z), a5);      \
  a6 = fmaf(v, blo(xb.w), a6); a7 = fmaf(v, bhi(xb.w), a7);

__global__ __launch_bounds__(256) void prop_kernel_bf16(
    const uint4* __restrict__ xin, uint4* __restrict__ xout,
    const uint4* __restrict__ hb, const int2* __restrict__ edges,
    const int* __restrict__ rp) {
  const int t = blockIdx.x * 256 + threadIdx.x;
  const int node = t / TPN;
  if (node >= NN) return;
  const int g = t - node * TPN;  // class-group 0..4 (classes 8g..8g+7)
  const int e0 = rp[node], e1 = rp[node + 1];
  float a0 = 0.f, a1 = 0.f, a2 = 0.f, a3 = 0.f;
  float a4 = 0.f, a5 = 0.f, a6 = 0.f, a7 = 0.f;
  int e = e0;
  // prologue: align e to even for int4 edge-pair loads
  if ((e & 1) && e < e1) {
    int2 ed = edges[e];
    float v = __int_as_float(ed.y);
    uint4 xb = xin[ed.x * TPN + g];
    FMA8(v, xb);
    ++e;
  }
  const int4* edges2 = (const int4*)edges;
  while (e + 2 <= e1) {
    int4 ep = edges2[e >> 1];
    float v0 = __int_as_float(ep.y);
    float v1 = __int_as_float(ep.w);
    uint4 xb0 = xin[ep.x * TPN + g];
    uint4 xb1 = xin[ep.z * TPN + g];
    FMA8(v0, xb0);
    FMA8(v1, xb1);
    e += 2;
  }
  if (e < e1) {
    int2 ed = edges[e];
    float v = __int_as_float(ed.y);
    uint4 xb = xin[ed.x * TPN + g];
    FMA8(v, xb);
  }
  uint4 hh = hb[node * TPN + g];
  uint4 r;
  r.x = pk(fmaf(0.9f, a0, 0.1f * blo(hh.x)), fmaf(0.9f, a1, 0.1f * bhi(hh.x)));
  r.y = pk(fmaf(0.9f, a2, 0.1f * blo(hh.y)), fmaf(0.9f, a3, 0.1f * bhi(hh.y)));
  r.z = pk(fmaf(0.9f, a4, 0.1f * blo(hh.z)), fmaf(0.9f, a5, 0.1f * bhi(hh.z)));
  r.w = pk(fmaf(0.9f, a6, 0.1f * blo(hh.w)), fmaf(0.9f, a7, 0.1f * bhi(hh.w)));
  xout[node * TPN + g] = r;
}

// ---------------------------------------------------------------------------
// log_softmax over 40 classes (bf16 in, fp32 out), one thread per node
// ---------------------------------------------------------------------------
__global__ __launch_bounds__(256) void logsm_kernel(
    const ushort4* __restrict__ X, float* __restrict__ out) {
  const int node = blockIdx.x * 256 + threadIdx.x;
  if (node >= NN) return;
  float v[NCLS];
#pragma unroll
  for (int q = 0; q < 10; ++q) {
    ushort4 a = X[node * 10 + q];
    v[q * 4] = bf2f(a.x);
    v[q * 4 + 1] = bf2f(a.y);
    v[q * 4 + 2] = bf2f(a.z);
    v[q * 4 + 3] = bf2f(a.w);
  }
  float m = v[0];
#pragma unroll
  for (int j = 1; j < NCLS; ++j) m = fmaxf(m, v[j]);
  float s = 0.f;
#pragma unroll
  for (int j = 0; j < NCLS; ++j) s += expf(v[j] - m);
  const float l = m + logf(s);
  float4* o4 = (float4*)(out + (long)node * NCLS);
#pragma unroll
  for (int q = 0; q < 10; ++q)
    o4[q] = make_float4(v[q * 4] - l, v[q * 4 + 1] - l, v[q * 4 + 2] - l,
                        v[q * 4 + 3] - l);
}

// ---------------------------------------------------------------------------
// Launch
// ---------------------------------------------------------------------------
extern "C" void kernel_launch(void* const* d_in, const int* in_sizes, int n_in,
                              void* d_out, int out_size, void* d_ws,
                              size_t ws_size, hipStream_t stream) {
  const float* F = (const float*)d_in[0];
  const int* EI = (const int*)d_in[1];
  const float* EV = (const float*)d_in[2];
  const float* W1 = (const float*)d_in[3];
  const float* b1 = (const float*)d_in[4];
  const float* W2 = (const float*)d_in[5];
  const float* b2 = (const float*)d_in[6];
  float* out = (float*)d_out;
  char* ws = (char*)d_ws;

  // ws layout, phase-aliased:
  //   build:  STAGED [0,25.6M)  HIST@42M  BASE@43.7M  BSUM/BOFF@45.4M
  //           EDG [48M,73.6M)  RP@73.6M
  //   gemms:  H [16M,41.6M)  X0b@76M (bf16)
  //   prop :  X0b (=h AND x_0, bf16)  XAb/XBb bf16 @84/92M  EDG, RP
  int2* STAGED = (int2*)(ws + 0);
  float* H = (float*)(ws + 16000000);
  int* HIST = (int*)(ws + 42000000);
  int* BASE = (int*)(ws + 43700000);
  int* BSUM = (int*)(ws + 45400000);
  int* BOFF = (int*)(ws + 45402048);
  int2* EDG = (int2*)(ws + 48000000);
  int* RP = (int*)(ws + 73600000);
  uint4* X0b = (uint4*)(ws + 76000000);  // NN*40 bf16 = 8 MB
  uint4* XAb = (uint4*)(ws + 84000000);
  uint4* XBb = (uint4*)(ws + 92000000);  // ends at 100 MB

  const int* ROW = EI;       // edge_index[0]
  const int* COL = EI + NE;  // edge_index[1]

  // --- CSR build ---
  p1_count<<<NCH, 256, 0, stream>>>(ROW, HIST);
  p2a_scan<<<NSB, 1024, 0, stream>>>(HIST, BASE, BSUM);
  p2b_scan<<<1, 512, 0, stream>>>(BSUM, BOFF);
  p2c_add<<<NSB, 1024, 0, stream>>>(BASE, BOFF);
  p3_scatter<<<NCH, 256, 0, stream>>>(ROW, COL, EV, BASE, STAGED);
  p4_emit<<<NB2, 256, 0, stream>>>(BASE, STAGED, EDG, RP);

  // --- MLP ---
  gemm1_kernel<<<(NN + 63) / 64, 256, 0, stream>>>(F, W1, b1, H);
  gemm2_kernel<<<(NN + 255) / 256, 256, 0, stream>>>(H, W2, b2,
                                                     (ushort4*)X0b);

  // --- propagation (bf16 x, bf16 h) ---
  const int tgrid = (NN * TPN + 255) / 256;
  const uint4* cur_in = X0b;
  uint4* bufs[2] = {XAb, XBb};
  for (int it = 0; it < 10; ++it) {
    uint4* o = bufs[it & 1];
    prop_kernel_bf16<<<tgrid, 256, 0, stream>>>(cur_in, o, X0b, EDG, RP);
    cur_in = o;
  }
  logsm_kernel<<<(NN + 255) / 256, 256, 0, stream>>>((const ushort4*)cur_in,
                                                     out);
}